// Round 11
// baseline (222.520 us; speedup 1.0000x reference)
//
#include <hip/hip_runtime.h>
#include <hip/hip_bf16.h>
#include <hip/hip_cooperative_groups.h>

namespace cg = cooperative_groups;

// MessagePassing: out[t] += x[s] for each edge (t, s), D=64.
// edge_index: [2, E] int32 (row 0 = targets, row 1 = sources), x: [N, 64] f32.
//
// Single cooperative kernel (512 blocks x 1024 thr = 2/CU exactly),
// grid.sync() between phases. A) init bucket cursors; B) partition edges into
// fixed-cap bucket regions (LDS-staged flush, wave-0 shfl scan); C) per-bucket
// counting sort in LDS + register accumulation (zero f32 atomics), one
// coalesced store per node; D) exact spill fixup (~always 0 entries).
// Round-11 fix: round 10's host guard compared E against total grid staging
// (E > 524288 -> always took the atomic fallback; we benched the baseline!).
// Real constraint is per-bucket: epb = ceil(E/NB2) <= min(EPT*FTHR, CAP).

#define D 64
#define NB2 512         // buckets == blocks
#define GPB_MAX 128     // max nodes/bucket (N <= 65536 for u16 packing)
#define CAP 2048        // pair words per bucket region
#define FTHR 1024       // threads per block
#define EPT 2           // edges/thread in part phase
#define SPILL_MAX 65536

union SharedU {
    struct {                       // phase B: partition
        unsigned sw[CAP];          // 8KB staged pair words
        unsigned short sb[CAP];    // 4KB staged bucket ids
        int h[NB2];                // per-bucket counts
        int coff[NB2];             // exclusive offsets (stable)
        int crun[NB2];             // running cursors
        int gbase[NB2];            // reserved global bases
    } p;                           // 28KB
    struct {                       // phase C: bucket sort + accumulate
        unsigned sp[CAP];          // 8KB staged pair words
        unsigned short ss[CAP];    // 4KB sorted src ids
        int cnt2[GPB_MAX];
        int wpos[GPB_MAX];
        int roff[GPB_MAX + 1];
    } c;                           // ~13.5KB
};

__global__ __launch_bounds__(FTHR, 8) void fused_kernel(
        const int* __restrict__ tgt, const int* __restrict__ src,
        int* __restrict__ brun, unsigned* __restrict__ pairs,
        int* __restrict__ spill, int* __restrict__ scnt,
        const float* __restrict__ x, float* __restrict__ out,
        int E, int N, int gpb) {
    __shared__ SharedU u;
    cg::grid_group grid = cg::this_grid();
    int b = blockIdx.x;
    int t = threadIdx.x;
    int wid = t >> 6, lane = t & 63;

    // ---- phase A: init bucket cursors + spill count ----
    if (t == 0) brun[b] = b * CAP;
    if (b == 0 && t == 1) scnt[0] = 0;
    grid.sync();

    // ---- phase B: partition edges into bucket regions ----
    int epb = (E + NB2 - 1) / NB2;          // <= min(EPT*FTHR, CAP), enforced
    int base = b * epb;
    int nitems = E - base;
    if (nitems > epb) nitems = epb;
    if (nitems < 0) nitems = 0;

    for (int i = t; i < NB2; i += FTHR) u.p.h[i] = 0;
    __syncthreads();

    int myb[EPT]; unsigned myw[EPT];
    #pragma unroll
    for (int k = 0; k < EPT; ++k) {
        myb[k] = -1; myw[k] = 0;
        int j = t + k * FTHR;
        if (j < nitems) {
            int e = base + j;
            unsigned tg = (unsigned)tgt[e];
            unsigned s  = (unsigned)src[e];
            int bk = (int)(tg / (unsigned)gpb);
            myb[k] = bk;
            myw[k] = ((tg - (unsigned)bk * (unsigned)gpb) << 16) | s;
            atomicAdd(&u.p.h[bk], 1);
        }
    }
    __syncthreads();

    // wave-0 shfl scan of h[512] (8 entries/lane)
    if (wid == 0) {
        int b8 = lane * 8;
        int cvals[8], pre[8], s = 0;
        #pragma unroll
        for (int k = 0; k < 8; ++k) { cvals[k] = u.p.h[b8 + k]; pre[k] = s; s += cvals[k]; }
        int run = s;
        #pragma unroll
        for (int d2 = 1; d2 < 64; d2 <<= 1) {
            int v = __shfl_up(run, d2); if (lane >= d2) run += v;
        }
        int excl = run - s;
        #pragma unroll
        for (int k = 0; k < 8; ++k) {
            int v2 = excl + pre[k];
            u.p.coff[b8 + k] = v2;
            u.p.crun[b8 + k] = v2;
        }
    }
    if (t < NB2) {
        int hv = u.p.h[t];
        u.p.gbase[t] = hv ? atomicAdd(&brun[t], hv) : 0;
    }
    __syncthreads();

    // stage (bucket-grouped within block)
    #pragma unroll
    for (int k = 0; k < EPT; ++k) {
        if (myb[k] >= 0) {
            int pos = atomicAdd(&u.p.crun[myb[k]], 1);
            u.p.sw[pos] = myw[k];
            u.p.sb[pos] = (unsigned short)myb[k];
        }
    }
    __syncthreads();

    // flush: consecutive i within a bucket run -> consecutive global dst
    for (int i = t; i < nitems; i += FTHR) {
        int bk = u.p.sb[i];
        int dst = u.p.gbase[bk] + (i - u.p.coff[bk]);
        if (dst < (bk + 1) * CAP) {
            pairs[dst] = u.p.sw[i];
        } else {
            int sp2 = atomicAdd(scnt, 1);
            if (sp2 < SPILL_MAX) {
                unsigned w = u.p.sw[i];
                spill[2 * sp2]     = bk * gpb + (int)(w >> 16);
                spill[2 * sp2 + 1] = (int)(w & 0xffffu);
            }
        }
    }
    grid.sync();

    // ---- phase C: per-bucket counting sort + register accumulate ----
    int lo = b * gpb;
    if (lo < N) {
        int hi = lo + gpb; if (hi > N) hi = N;
        int nn = hi - lo;
        int m = brun[b] - b * CAP;
        if (m > CAP) m = CAP;       // excess went to the spill list

        for (int i = t; i < m; i += FTHR) u.c.sp[i] = pairs[b * CAP + i];
        if (t < GPB_MAX) u.c.cnt2[t] = 0;
        __syncthreads();
        for (int i = t; i < m; i += FTHR) atomicAdd(&u.c.cnt2[u.c.sp[i] >> 16], 1);
        __syncthreads();
        if (wid == 0) {
            int c0 = u.c.cnt2[lane], c1 = u.c.cnt2[64 + lane];
            int s0c = c0, s1c = c1;
            #pragma unroll
            for (int d2 = 1; d2 < 64; d2 <<= 1) {
                int v = __shfl_up(s0c, d2); if (lane >= d2) s0c += v;
            }
            int tot0 = __shfl(s0c, 63);
            #pragma unroll
            for (int d2 = 1; d2 < 64; d2 <<= 1) {
                int v = __shfl_up(s1c, d2); if (lane >= d2) s1c += v;
            }
            u.c.roff[lane] = s0c - c0;        u.c.wpos[lane] = s0c - c0;
            u.c.roff[64 + lane] = tot0 + s1c - c1;
            u.c.wpos[64 + lane] = tot0 + s1c - c1;
            if (lane == 63) u.c.roff[GPB_MAX] = tot0 + s1c;
        }
        __syncthreads();
        for (int i = t; i < m; i += FTHR) {
            unsigned w = u.c.sp[i];
            int pos = atomicAdd(&u.c.wpos[w >> 16], 1);
            u.c.ss[pos] = (unsigned short)(w & 0xffffu);
        }
        __syncthreads();

        float acc[8];
        #pragma unroll
        for (int r = 0; r < 8; ++r) acc[r] = 0.f;
        #pragma unroll
        for (int r = 0; r < 8; ++r) {
            int node = wid + (r << 4);           // wave-uniform
            if (node < nn) {
                int rs = u.c.roff[node], re = u.c.roff[node + 1];
                float a = acc[r];
                for (int j = rs; j < re; j += 8) {
                    int idv[8]; float vv[8];
                    #pragma unroll
                    for (int k = 0; k < 8; ++k) {
                        int jj = j + k;
                        idv[k] = u.c.ss[(jj < re) ? jj : rs];
                    }
                    #pragma unroll
                    for (int k = 0; k < 8; ++k)
                        vv[k] = x[idv[k] * D + lane];
                    #pragma unroll
                    for (int k = 0; k < 8; ++k)
                        if (j + k < re) a += vv[k];
                }
                acc[r] = a;
            }
        }
        // one coalesced store per node (zeros included)
        #pragma unroll
        for (int r = 0; r < 8; ++r) {
            int node = wid + (r << 4);
            if (node < nn) out[(size_t)(lo + node) * D + lane] = acc[r];
        }
    }
    grid.sync();

    // ---- phase D: exact spill fixup (normally zero entries) ----
    int n = scnt[0]; if (n > SPILL_MAX) n = SPILL_MAX;
    if (n > 0) {
        int gw = (b * FTHR + t) >> 6;
        int nw = (NB2 * FTHR) >> 6;
        for (int i = gw; i < n; i += nw) {
            int tg2 = spill[2 * i], s2 = spill[2 * i + 1];
            atomicAdd(&out[(size_t)tg2 * D + lane], x[(size_t)s2 * D + lane]);
        }
    }
}

// Fallback: direct atomic scatter-add.
__global__ void mp_scatter_add_kernel(const int* __restrict__ tgt,
                                      const int* __restrict__ src,
                                      const float* __restrict__ x,
                                      float* __restrict__ out,
                                      int E) {
    long long tid = (long long)blockIdx.x * blockDim.x + threadIdx.x;
    int e = (int)(tid >> 6);
    int d = (int)(tid & 63);
    if (e >= E) return;
    atomicAdd(&out[(long long)tgt[e] * D + d], x[(long long)src[e] * D + d]);
}

extern "C" void kernel_launch(void* const* d_in, const int* in_sizes, int n_in,
                              void* d_out, int out_size, void* d_ws, size_t ws_size,
                              hipStream_t stream) {
    const int* edge_index = (const int*)d_in[0];   // [2, E]
    const float* x        = (const float*)d_in[1]; // [N, 64]
    float* out            = (float*)d_out;         // [N, 64]

    int E = in_sizes[0] / 2;
    int N = out_size / D;
    const int* tgt = edge_index;       // edge_index[0]
    const int* src = edge_index + E;   // edge_index[1]

    int gpb = (N + NB2 - 1) / NB2;     // nodes per bucket (98 for N=50000)
    int epb = (E + NB2 - 1) / NB2;     // edges per part block (1563 for E=800k)

    // ws layout (ints): brun[512] | scnt[4] | pairs[512*CAP] | spill[2*SPILL_MAX]
    size_t need = (size_t)(NB2 + 4 + (size_t)NB2 * CAP + 2 * SPILL_MAX) * sizeof(int);

    if (N > 65536 || gpb > GPB_MAX || epb > EPT * FTHR || epb > CAP ||
        ws_size < need) {
        hipMemsetAsync(d_out, 0, (size_t)out_size * sizeof(float), stream);
        long long total = (long long)E * D;
        long long grid = (total + 255) / 256;
        mp_scatter_add_kernel<<<(dim3)(unsigned)grid, 256, 0, stream>>>(tgt, src, x, out, E);
        return;
    }

    int* brun = (int*)d_ws;
    int* scnt = brun + NB2;
    unsigned* pairs = (unsigned*)(scnt + 4);
    int* spill = (int*)(pairs + (size_t)NB2 * CAP);

    void* args[] = { (void*)&tgt, (void*)&src, (void*)&brun, (void*)&pairs,
                     (void*)&spill, (void*)&scnt, (void*)&x, (void*)&out,
                     (void*)&E, (void*)&N, (void*)&gpb };
    hipLaunchCooperativeKernel((const void*)fused_kernel, dim3(NB2), dim3(FTHR),
                               args, 0, stream);
}

// Round 12
// 46.183 us; speedup vs baseline: 4.8182x; 4.8182x over previous
//
#include <hip/hip_runtime.h>
#include <hip/hip_bf16.h>

// MessagePassing: out[t] += x[s] for each edge (t, s), D=64.
// edge_index: [2, E] int32 (row 0 = targets, row 1 = sources), x: [N, 64] f32.
//
// Round-12: revert to the split pipeline (round 9, 47.5us; round 11's fused
// coop kernel hit VGPR=16 from __launch_bounds__(1024,8) -> spilled the
// 8-deep gather pipeline -> 205us). Overhead shaved instead:
//  - init kernel -> hipMemsetAsync (brun/scnt zeroed; offsets are counts)
//  - spill fixup folded into bsum's tail (own-bucket scan; ~always 0 entries)
//  - part's 18-barrier Hillis-Steele -> wave-0 shfl scan (5 barriers total)
// bsum unchanged: counting sort in LDS + register accumulation, plain
// __launch_bounds__(1024) so the compiler keeps the pipeline in registers.

#define D 64
#define NB2 512         // coarse buckets
#define GPB_MAX 128     // max nodes/bucket (N <= 65536 for u16 packing)
#define CAP 2048        // pair words per bucket region
#define EPB 4096        // edges per part block
#define PTHR 1024       // part threads
#define BTHR 1024       // bsum threads
#define SPILL_MAX 65536

// ---- 1: partition edges into fixed-cap bucket regions (LDS-staged flush) ----
// pair word = (local_tgt << 16) | src   (requires N <= 65536)
__global__ __launch_bounds__(PTHR) void part_kernel(const int* __restrict__ tgt,
                                                    const int* __restrict__ src,
                                                    int* __restrict__ brun,
                                                    unsigned* __restrict__ pairs,
                                                    int* __restrict__ spill,
                                                    int* __restrict__ scnt,
                                                    int E, int gpb) {
    __shared__ int h[NB2];
    __shared__ int coff[NB2];
    __shared__ int crun[NB2];
    __shared__ int gbase[NB2];
    __shared__ unsigned sw[EPB];
    __shared__ unsigned short sb[EPB];
    int t = threadIdx.x;
    int wid = t >> 6, lane = t & 63;
    int base = blockIdx.x * EPB;
    int nitems = E - base;
    if (nitems > EPB) nitems = EPB;
    if (nitems < 0) nitems = 0;

    for (int i = t; i < NB2; i += PTHR) h[i] = 0;
    __syncthreads();

    int myb[EPB / PTHR];
    unsigned myw[EPB / PTHR];
    #pragma unroll
    for (int k = 0; k < EPB / PTHR; ++k) {
        myb[k] = -1; myw[k] = 0;
        int j = t + k * PTHR;
        if (j < nitems) {
            int e = base + j;
            unsigned tg = (unsigned)tgt[e];
            unsigned s  = (unsigned)src[e];
            int bk = (int)(tg / (unsigned)gpb);
            myb[k] = bk;
            myw[k] = ((tg - (unsigned)bk * (unsigned)gpb) << 16) | s;
            atomicAdd(&h[bk], 1);
        }
    }
    __syncthreads();

    // wave-0 shfl scan of h[512] (8 entries/lane); gbase reservation by t<512
    if (wid == 0) {
        int b8 = lane * 8;
        int cvals[8], pre[8], s = 0;
        #pragma unroll
        for (int k = 0; k < 8; ++k) { cvals[k] = h[b8 + k]; pre[k] = s; s += cvals[k]; }
        int run = s;
        #pragma unroll
        for (int d2 = 1; d2 < 64; d2 <<= 1) {
            int v = __shfl_up(run, d2); if (lane >= d2) run += v;
        }
        int excl = run - s;
        #pragma unroll
        for (int k = 0; k < 8; ++k) {
            int v2 = excl + pre[k];
            coff[b8 + k] = v2;
            crun[b8 + k] = v2;
        }
    }
    if (t < NB2) {
        int hv = h[t];
        gbase[t] = hv ? atomicAdd(&brun[t], hv) : 0;   // brun zeroed by memset
    }
    __syncthreads();

    // place into staging (bucket-grouped within block)
    #pragma unroll
    for (int k = 0; k < EPB / PTHR; ++k) {
        if (myb[k] >= 0) {
            int pos = atomicAdd(&crun[myb[k]], 1);
            sw[pos] = myw[k];
            sb[pos] = (unsigned short)myb[k];
        }
    }
    __syncthreads();

    // flush: consecutive i within a bucket run -> consecutive global dst
    for (int i = t; i < nitems; i += PTHR) {
        int bk = sb[i];
        int dstl = gbase[bk] + (i - coff[bk]);     // count-relative offset
        if (dstl < CAP) {
            pairs[bk * CAP + dstl] = sw[i];
        } else {
            int sp2 = atomicAdd(scnt, 1);
            if (sp2 < SPILL_MAX) {
                unsigned w = sw[i];
                spill[2 * sp2]     = bk * gpb + (int)(w >> 16);
                spill[2 * sp2 + 1] = (int)(w & 0xffffu);
            }
        }
    }
}

// ---- 2: per-bucket counting sort (LDS) + register accumulate + spill tail ----
// Wave wid owns nodes wid+16r (r<8, static). Lane = feature dim.
__global__ __launch_bounds__(BTHR) void bsum_kernel(const int* __restrict__ brun,
                                                    const unsigned* __restrict__ pairs,
                                                    const int* __restrict__ spill,
                                                    const int* __restrict__ scnt,
                                                    const float* __restrict__ x,
                                                    float* __restrict__ out,
                                                    int N, int gpb) {
    __shared__ unsigned sp[CAP];         // 8KB: staged pair words
    __shared__ unsigned short ss[CAP];   // 4KB: sorted src ids
    __shared__ int cnt2[GPB_MAX];
    __shared__ int roff[GPB_MAX + 1];
    __shared__ int wpos[GPB_MAX];
    int b = blockIdx.x;
    int t = threadIdx.x;
    int wid = t >> 6;
    int lane = t & 63;
    int lo = b * gpb;

    if (lo < N) {
        int hi = lo + gpb; if (hi > N) hi = N;
        int nn = hi - lo;
        int m = brun[b];
        if (m > CAP) m = CAP;       // excess went to the spill list

        // stage pair words (coalesced), zero counters
        for (int i = t; i < m; i += BTHR) sp[i] = pairs[b * CAP + i];
        if (t < GPB_MAX) cnt2[t] = 0;
        __syncthreads();
        // histogram of local targets (single-lane int atomics, from LDS)
        for (int i = t; i < m; i += BTHR) atomicAdd(&cnt2[sp[i] >> 16], 1);
        __syncthreads();
        // exclusive scan of 128 counters by wave 0 (shfl scan)
        if (wid == 0) {
            int c0 = cnt2[lane], c1 = cnt2[64 + lane];
            int s0c = c0, s1c = c1;
            #pragma unroll
            for (int d2 = 1; d2 < 64; d2 <<= 1) {
                int v = __shfl_up(s0c, d2); if (lane >= d2) s0c += v;
            }
            int tot0 = __shfl(s0c, 63);
            #pragma unroll
            for (int d2 = 1; d2 < 64; d2 <<= 1) {
                int v = __shfl_up(s1c, d2); if (lane >= d2) s1c += v;
            }
            roff[lane] = s0c - c0;        wpos[lane] = s0c - c0;
            roff[64 + lane] = tot0 + s1c - c1;
            wpos[64 + lane] = tot0 + s1c - c1;
            if (lane == 63) roff[GPB_MAX] = tot0 + s1c;
        }
        __syncthreads();
        // scatter src ids into sorted order (u16, LDS->LDS)
        for (int i = t; i < m; i += BTHR) {
            unsigned w = sp[i];
            int pos = atomicAdd(&wpos[w >> 16], 1);
            ss[pos] = (unsigned short)(w & 0xffffu);
        }
        __syncthreads();

        float acc[8];
        #pragma unroll
        for (int r = 0; r < 8; ++r) acc[r] = 0.f;
        // register accumulation over each owned node's contiguous run
        #pragma unroll
        for (int r = 0; r < 8; ++r) {
            int node = wid + (r << 4);           // wave-uniform
            if (node < nn) {
                int rs = roff[node], re = roff[node + 1];
                float a = acc[r];
                for (int j = rs; j < re; j += 8) {
                    int idv[8]; float vv[8];
                    #pragma unroll
                    for (int k = 0; k < 8; ++k) {
                        int jj = j + k;
                        idv[k] = ss[(jj < re) ? jj : rs];
                    }
                    #pragma unroll
                    for (int k = 0; k < 8; ++k)
                        vv[k] = x[idv[k] * D + lane];
                    #pragma unroll
                    for (int k = 0; k < 8; ++k)
                        if (j + k < re) a += vv[k];
                }
                acc[r] = a;
            }
        }
        // one coalesced store per node (zeros included)
        #pragma unroll
        for (int r = 0; r < 8; ++r) {
            int node = wid + (r << 4);
            if (node < nn) out[(size_t)(lo + node) * D + lane] = acc[r];
        }
    }

    // ---- spill tail: this bucket's overflow edges (normally zero) ----
    __syncthreads();   // stores above completed (vmcnt drained before barrier)
    int n = scnt[0]; if (n > SPILL_MAX) n = SPILL_MAX;
    if (n > 0) {
        for (int i = wid; i < n; i += 16) {
            int tg2 = spill[2 * i];
            if (tg2 / gpb == b) {
                int s2 = spill[2 * i + 1];
                atomicAdd(&out[(size_t)tg2 * D + lane], x[(size_t)s2 * D + lane]);
            }
        }
    }
}

// Fallback: direct atomic scatter-add.
__global__ void mp_scatter_add_kernel(const int* __restrict__ tgt,
                                      const int* __restrict__ src,
                                      const float* __restrict__ x,
                                      float* __restrict__ out,
                                      int E) {
    long long tid = (long long)blockIdx.x * blockDim.x + threadIdx.x;
    int e = (int)(tid >> 6);
    int d = (int)(tid & 63);
    if (e >= E) return;
    atomicAdd(&out[(long long)tgt[e] * D + d], x[(long long)src[e] * D + d]);
}

extern "C" void kernel_launch(void* const* d_in, const int* in_sizes, int n_in,
                              void* d_out, int out_size, void* d_ws, size_t ws_size,
                              hipStream_t stream) {
    const int* edge_index = (const int*)d_in[0];   // [2, E]
    const float* x        = (const float*)d_in[1]; // [N, 64]
    float* out            = (float*)d_out;         // [N, 64]

    int E = in_sizes[0] / 2;
    int N = out_size / D;
    const int* tgt = edge_index;       // edge_index[0]
    const int* src = edge_index + E;   // edge_index[1]

    int gpb = (N + NB2 - 1) / NB2;     // nodes per bucket (98 for N=50000)

    // ws layout (ints): brun[512] | scnt[4] | pairs[512*CAP] | spill[2*SPILL_MAX]
    size_t need = (size_t)(NB2 + 4 + (size_t)NB2 * CAP + 2 * SPILL_MAX) * sizeof(int);

    if (N > 65536 || gpb > GPB_MAX || ws_size < need) {
        hipMemsetAsync(d_out, 0, (size_t)out_size * sizeof(float), stream);
        long long total = (long long)E * D;
        long long grid = (total + 255) / 256;
        mp_scatter_add_kernel<<<(dim3)(unsigned)grid, 256, 0, stream>>>(tgt, src, x, out, E);
        return;
    }

    int* brun = (int*)d_ws;
    int* scnt = brun + NB2;
    unsigned* pairs = (unsigned*)(scnt + 4);
    int* spill = (int*)(pairs + (size_t)NB2 * CAP);

    // zero bucket cursors + spill count (counts are relative to b*CAP)
    hipMemsetAsync(brun, 0, (NB2 + 4) * sizeof(int), stream);

    int GE = (E + EPB - 1) / EPB;
    part_kernel<<<GE, PTHR, 0, stream>>>(tgt, src, brun, pairs, spill, scnt, E, gpb);
    bsum_kernel<<<NB2, BTHR, 0, stream>>>(brun, pairs, spill, scnt, x, out, N, gpb);
}